// Round 4
// baseline (228.842 us; speedup 1.0000x reference)
//
#include <hip/hip_runtime.h>
#include <stdint.h>

#define GAS __attribute__((address_space(1)))
#define LAS __attribute__((address_space(3)))

typedef unsigned short u16;
typedef __attribute__((ext_vector_type(8))) __bf16 bf16x8;
typedef __attribute__((ext_vector_type(4))) float f32x4;
typedef __attribute__((ext_vector_type(2))) unsigned int u32x2;
typedef __attribute__((ext_vector_type(4))) unsigned int u32x4;

#define SEQ 2048
#define WORD 1024
#define EMBED 128
#define NHEAD 16

__device__ __forceinline__ u16 f2b(float f) {
  return __builtin_bit_cast(u16, (__bf16)f);
}

__device__ __forceinline__ unsigned cvt_pk_bf16(float lo, float hi) {
  unsigned r;
  asm("v_cvt_pk_bf16_f32 %0, %1, %2" : "=v"(r) : "v"(lo), "v"(hi));
  return r;
}

// ---------------- cast x (fp32 -> bf16), 4 elems/thread ----------------
__global__ __launch_bounds__(256) void cast_x_kernel(const float* __restrict__ x,
                                                     u16* __restrict__ xb) {
  int i = (blockIdx.x * 256 + threadIdx.x) * 4;
  float4 v = *(const float4*)(x + i);
  ushort4 o;
  o.x = f2b(v.x); o.y = f2b(v.y); o.z = f2b(v.z); o.w = f2b(v.w);
  *(ushort4*)(xb + i) = o;
}

// ------------- transpose+cast: src[R][C] fp32 -> dst[C][R] bf16 --------
// zsel: 0 -> plain (proj). 1 -> batched QKV weights (z selects W and head).
__global__ __launch_bounds__(256) void transpose_cast_kernel(
    const float* __restrict__ s0, const float* __restrict__ s1,
    const float* __restrict__ s2, u16* __restrict__ d0, u16* __restrict__ d1,
    u16* __restrict__ d2, int R, int C, long stride, int zsel) {
  __shared__ float tile[32][33];
  const float* s;
  u16* d;
  if (zsel) {
    int z = blockIdx.z;
    int wsel = z >> 4, hh = z & 15;
    s = (wsel == 0 ? s0 : wsel == 1 ? s1 : s2) + (long)hh * stride;
    d = (wsel == 0 ? d0 : wsel == 1 ? d1 : d2) + (long)hh * stride;
  } else {
    s = s0; d = d0;
  }
  int r0 = blockIdx.x * 32, c0 = blockIdx.y * 32;
  int tx = threadIdx.x & 31, ty = threadIdx.x >> 5;  // ty 0..7
#pragma unroll
  for (int i = 0; i < 4; ++i)
    tile[ty + i * 8][tx] = s[(long)(r0 + ty + i * 8) * C + c0 + tx];
  __syncthreads();
#pragma unroll
  for (int i = 0; i < 4; ++i)
    d[(long)(c0 + ty + i * 8) * R + r0 + tx] = f2b(tile[tx][ty + i * 8]);
}

// ---------------- generic 128x128-tile GEMM: C = (A·B^T + bias) * scale ----
// A: [*, lda] k-contiguous (tile rows), B: [*, ldb] k-contiguous (tile cols).
// BK=64, XOR-swizzled LDS (chunk c -> c ^ (r&7)), global_load_lds width 16.
template <typename OUT>
__device__ __forceinline__ void gemm128(const u16* __restrict__ A, const u16* __restrict__ B,
                                        OUT* __restrict__ C, int lda, int ldb, int ldc,
                                        int ksteps, const float* biasN, const float* biasM,
                                        float scale) {
  __shared__ u16 lA[128 * 64];
  __shared__ u16 lB[128 * 64];
  const int tid = threadIdx.x;
  const int l = tid & 63, w = tid >> 6;
  const int quad = l >> 4, ln = l & 15;
  const int wm = w >> 1, wn = w & 1;
  f32x4 acc[4][4] = {};
  for (int ks = 0; ks < ksteps; ++ks) {
    const u16* Ak = A + ks * 64;
    const u16* Bk = B + ks * 64;
    __syncthreads();  // prior-iter LDS reads complete before overwrite
#pragma unroll
    for (int i = 0; i < 4; ++i) {
      int idx = w * 256 + i * 64 + l;        // 16B-chunk index 0..1023
      int r = idx >> 3, cp = idx & 7;
      int cg = cp ^ (r & 7);                 // global chunk for this LDS slot
      __builtin_amdgcn_global_load_lds((const GAS void*)(Ak + (long)r * lda + cg * 8),
                                       (LAS void*)(lA + (w * 256 + i * 64) * 8), 16, 0, 0);
      __builtin_amdgcn_global_load_lds((const GAS void*)(Bk + (long)r * ldb + cg * 8),
                                       (LAS void*)(lB + (w * 256 + i * 64) * 8), 16, 0, 0);
    }
    __syncthreads();
    bf16x8 af[2][4], bfv[2][4];
#pragma unroll
    for (int kc = 0; kc < 2; ++kc) {
#pragma unroll
      for (int i = 0; i < 4; ++i) {
        int c = kc * 4 + quad;
        int rm = wm * 64 + i * 16 + ln;
        af[kc][i] = *(const bf16x8*)(lA + rm * 64 + ((c ^ (rm & 7)) * 8));
        int rn = wn * 64 + i * 16 + ln;
        bfv[kc][i] = *(const bf16x8*)(lB + rn * 64 + ((c ^ (rn & 7)) * 8));
      }
    }
#pragma unroll
    for (int kc = 0; kc < 2; ++kc)
#pragma unroll
      for (int i = 0; i < 4; ++i)
#pragma unroll
        for (int j = 0; j < 4; ++j)
          acc[i][j] = __builtin_amdgcn_mfma_f32_16x16x32_bf16(af[kc][i], bfv[kc][j],
                                                              acc[i][j], 0, 0, 0);
  }
  // epilogue: C row = wm*64+i*16+quad*4+reg, col = wn*64+j*16+ln (m89 C-layout)
#pragma unroll
  for (int i = 0; i < 4; ++i) {
#pragma unroll
    for (int j = 0; j < 4; ++j) {
      int row0 = wm * 64 + i * 16 + quad * 4;
      int col = wn * 64 + j * 16 + ln;
      float bn = biasN ? biasN[col] : 0.f;
#pragma unroll
      for (int reg = 0; reg < 4; ++reg) {
        int row = row0 + reg;
        float bm = biasM ? biasM[row] : 0.f;
        float v = (acc[i][j][reg] + bn + bm) * scale;
        if constexpr (sizeof(OUT) == 2)
          C[(long)row * ldc + col] = (OUT)f2b(v);
        else
          C[(long)row * ldc + col] = v;
      }
    }
  }
}

// ---------------- fused QKV projection (z: 0=Q,1=K,2=V^T) ----------------
// Q gets log2(e)/sqrt(E) folded in so attention can use exp2 directly.
__global__ __launch_bounds__(256, 3) void qkv_gemm_kernel(
    const u16* __restrict__ xb, const u16* __restrict__ Wqt, const u16* __restrict__ Wkt,
    const u16* __restrict__ Wvt, const float* __restrict__ bq, const float* __restrict__ bk,
    const float* __restrict__ bv, u16* __restrict__ Q, u16* __restrict__ Kb,
    u16* __restrict__ Vt) {
  const int t = blockIdx.x;   // tile index (m-tile for Q/K, n-tile for V)
  const int h = blockIdx.y;
  const int which = blockIdx.z;
  const float qscale = 0.12753042123789493f;  // log2(e)/sqrt(128)
  if (which == 0) {
    gemm128<u16>(xb + t * 128 * WORD, Wqt + h * EMBED * WORD,
                 Q + h * SEQ * EMBED + t * 128 * EMBED, WORD, WORD, EMBED,
                 WORD / 64, bq + h * EMBED, nullptr, qscale);
  } else if (which == 1) {
    gemm128<u16>(xb + t * 128 * WORD, Wkt + h * EMBED * WORD,
                 Kb + h * SEQ * EMBED + t * 128 * EMBED, WORD, WORD, EMBED,
                 WORD / 64, bk + h * EMBED, nullptr, 1.f);
  } else {
    // V^T[e][s] = sum_w Wvt[h][e][w] * x[s][w]  (A=Wvt rows e, B=x rows s)
    gemm128<u16>(Wvt + h * EMBED * WORD, xb + t * 128 * WORD,
                 Vt + h * EMBED * SEQ + t * 128, WORD, WORD, SEQ,
                 WORD / 64, nullptr, bv + h * EMBED, 1.f);
  }
}

// ---------------- flash attention v5: v4 with corrected permlane algebra ----
// R3 post-mortem: v4's P->PA redistribution used reversed permlane32 operands
// and swapped output words. Corrected derivation (ISA: permlane32_swap(dst,src)
// => new dst = [dst.q0, dst.q1, src.q0, src.q1], new src = [dst.q2, dst.q3,
// src.q2, src.q3]; permlane16_swap analogous on 16-lane rows):
//   t = permlane32_swap(a, b); u = permlane16_swap(t.x, t.y)
//   u.x = [a@q0, a@q2, b@q0, b@q2]  = PA word for j-pair {0,1} / {2,3}
//   u.y = [a@q1, a@q3, b@q1, b@q3]  = PA word for j-pair {4,5} / {6,7}
// paw = {u0.x, u1.x, u0.y, u1.y}. Verified by element trace (key 22:
// src (qs=1,b1.lo) -> t1.x.q3 -> u1.y.q2 = lane(qt=2) word3.lo ✓).
__global__ __launch_bounds__(512, 2) void attn_kernel(const u16* __restrict__ Q,
                                                      const u16* __restrict__ K,
                                                      const u16* __restrict__ V,  // V^T [h][e][s]
                                                      u16* __restrict__ Zs) {
  __shared__ __align__(16) char smem[67584];  // 64 KB K dbuf | 67.6 KB merge
  u16* lK = (u16*)smem;
  const int bid = blockIdx.x;
  const int swz = (bid & 7) * 32 + (bid >> 3);  // bijective, 2 heads per XCD
  const int h = swz >> 4, qb = swz & 15;        // qb: 128-row tile, 0..15
  const int tid = threadIdx.x;
  const int l = tid & 63, w = tid >> 6, quad = l >> 4, ln = l & 15;
  const int wr = w >> 1, wk = w & 1;            // row-group / key-group
  const u16* Qh = Q + h * SEQ * EMBED;
  const u16* Kh = K + h * SEQ * EMBED;
  const u16* Vh = V + h * EMBED * SEQ;
  const int q0 = qb * 128 + wr * 32;

  // cooperative stage of one 128-key K tile (32 KB) into lK[buf]: 4 gll/wave
  auto stage = [&](int buf, int sup) {
#pragma unroll
    for (int j = 0; j < 4; ++j) {
      int kb = j >> 1;                      // 0 = even 64-key tile, 1 = odd
      int cb = (j & 1) * 512 + w * 64;      // wave-uniform chunk base 0..1023
      int c = cb + l;
      int rk = c >> 4, cgk = (c & 15) ^ (rk & 15);
      __builtin_amdgcn_global_load_lds(
          (const GAS void*)(Kh + (sup * 128 + kb * 64 + rk) * EMBED + cgk * 8),
          (LAS void*)(lK + buf * 16384 + kb * 8192 + cb * 8), 16, 0, 0);
    }
  };

  // Q fragments in registers (frag layout: m/n=ln, k=quad*8+j); log2e/sqrt(E) folded
  bf16x8 qf[2][4];
#pragma unroll
  for (int rs = 0; rs < 2; ++rs)
#pragma unroll
    for (int kc = 0; kc < 4; ++kc)
      qf[rs][kc] = *(const bf16x8*)(Qh + (q0 + rs * 16 + ln) * EMBED + kc * 32 + quad * 8);

  f32x4 oacc[2][8] = {};
  float rsum[2] = {0.f, 0.f};

  stage(0, 0);  // prologue; loop-top vmcnt(20)+barrier covers the drain

  int cur = 0;
#pragma unroll 1
  for (int sup = 0; sup < SEQ / 128; ++sup) {
    // ---- V fragments direct from global (B-frag: n=e-row, k=key) ----
    bf16x8 vf[2][8];
#pragma unroll
    for (int kc = 0; kc < 2; ++kc)
#pragma unroll
      for (int es = 0; es < 8; ++es)
        vf[kc][es] = *(const bf16x8*)(Vh + (long)(es * 16 + ln) * SEQ + sup * 128 +
                                      wk * 64 + kc * 32 + quad * 8);
    __builtin_amdgcn_sched_barrier(0);  // keep vf issue ahead of staging
    if (sup + 1 < SEQ / 128) {
      stage(cur ^ 1, sup + 1);
      asm volatile("s_waitcnt vmcnt(20)" ::: "memory");  // stage(sup) retired
    } else {
      asm volatile("s_waitcnt vmcnt(16)" ::: "memory");
    }
    __builtin_amdgcn_s_barrier();       // all waves' stage(sup) visible
    __builtin_amdgcn_sched_barrier(0);  // no ds_read hoisted above this point

    const u16* myK = lK + cur * 16384 + wk * 8192;

    // ---- S^T = K'.Q (swapped): lane holds P[key=ns*16+quad*4+r][q=rs*16+ln] --
    f32x4 sacc[2][4] = {};
#pragma unroll
    for (int kc = 0; kc < 4; ++kc) {
      bf16x8 kf[4];
#pragma unroll
      for (int ns = 0; ns < 4; ++ns) {
        int kr = ns * 16 + ln;
        kf[ns] = *(const bf16x8*)(myK + kr * 128 + (((kc * 4 + quad) ^ (kr & 15)) * 8));
      }
      __builtin_amdgcn_s_setprio(1);
#pragma unroll
      for (int ns = 0; ns < 4; ++ns)
#pragma unroll
        for (int rs = 0; rs < 2; ++rs)
          sacc[rs][ns] = __builtin_amdgcn_mfma_f32_16x16x32_bf16(kf[ns], qf[rs][kc],
                                                                 sacc[rs][ns], 0, 0, 0);
      __builtin_amdgcn_s_setprio(0);
    }
    asm volatile("s_waitcnt lgkmcnt(0)" ::: "memory");
    __builtin_amdgcn_sched_barrier(0);
    __builtin_amdgcn_s_barrier();  // all waves done reading lK[cur]

    // ---- softmax + PA assembly + PV, fully in-register ----
#pragma unroll
    for (int rs = 0; rs < 2; ++rs) {
      float p[4][4];
#pragma unroll
      for (int ns = 0; ns < 4; ++ns)
#pragma unroll
        for (int r = 0; r < 4; ++r) p[ns][r] = exp2f(sacc[rs][ns][r]);
      float s0 = (p[0][0] + p[0][1]) + (p[0][2] + p[0][3]);
      float s1 = (p[1][0] + p[1][1]) + (p[1][2] + p[1][3]);
      float s2 = (p[2][0] + p[2][1]) + (p[2][2] + p[2][3]);
      float s3 = (p[3][0] + p[3][1]) + (p[3][2] + p[3][3]);
      rsum[rs] += (s0 + s1) + (s2 + s3);
#pragma unroll
      for (int kc = 0; kc < 2; ++kc) {
        // ns0 = kc*2 ("a" = keys [kc*32, kc*32+16)), ns1 = kc*2+1 ("b").
        // a0 = pack(r0,r1), a1 = pack(r2,r3); swap network per header comment.
        int n0 = kc * 2, n1 = kc * 2 + 1;
        unsigned a0 = cvt_pk_bf16(p[n0][0], p[n0][1]);
        unsigned a1 = cvt_pk_bf16(p[n0][2], p[n0][3]);
        unsigned b0 = cvt_pk_bf16(p[n1][0], p[n1][1]);
        unsigned b1 = cvt_pk_bf16(p[n1][2], p[n1][3]);
        u32x2 t0 = __builtin_amdgcn_permlane32_swap(a0, b0, false, false);
        u32x2 u0 = __builtin_amdgcn_permlane16_swap(t0.x, t0.y, false, false);
        u32x2 t1 = __builtin_amdgcn_permlane32_swap(a1, b1, false, false);
        u32x2 u1 = __builtin_amdgcn_permlane16_swap(t1.x, t1.y, false, false);
        u32x4 paw = {u0.x, u1.x, u0.y, u1.y};
        bf16x8 pa = __builtin_bit_cast(bf16x8, paw);
        __builtin_amdgcn_s_setprio(1);
#pragma unroll
        for (int es = 0; es < 8; ++es)
          oacc[rs][es] = __builtin_amdgcn_mfma_f32_16x16x32_bf16(pa, vf[kc][es],
                                                                 oacc[rs][es], 0, 0, 0);
        __builtin_amdgcn_s_setprio(0);
      }
    }
    cur ^= 1;
  }

  // ---- rowsum: reduce over quads (q=ln), broadcast to oacc row alignment ----
  float srl[2][4];
#pragma unroll
  for (int rs = 0; rs < 2; ++rs) {
    float t = rsum[rs] + __shfl(rsum[rs], l ^ 16);
    t = t + __shfl(t, l ^ 32);
#pragma unroll
    for (int r = 0; r < 4; ++r) srl[rs][r] = __shfl(t, quad * 4 + r);
  }

  // ---- merge wk=1 into wk=0 via LDS (reuses smem), divide by l, store ----
  __syncthreads();
  float* lO = (float*)smem;  // [wr][32][132] fp32, wr 0..3 -> 67.6 KB
  if (wk == 1) {
#pragma unroll
    for (int rs = 0; rs < 2; ++rs) {
#pragma unroll
      for (int es = 0; es < 8; ++es)
#pragma unroll
        for (int r = 0; r < 4; ++r)
          lO[wr * 4224 + (rs * 16 + quad * 4 + r) * 132 + es * 16 + ln] = oacc[rs][es][r];
      if (ln == 0)
#pragma unroll
        for (int r = 0; r < 4; ++r)
          lO[wr * 4224 + (rs * 16 + quad * 4 + r) * 132 + 128] = srl[rs][r];
    }
  }
  __syncthreads();
  if (wk == 0) {
#pragma unroll
    for (int rs = 0; rs < 2; ++rs)
#pragma unroll
      for (int r = 0; r < 4; ++r) {
        int lrow = rs * 16 + quad * 4 + r;
        float lsum = srl[rs][r] + lO[wr * 4224 + lrow * 132 + 128];
        float rl = 1.f / lsum;
        int srow = q0 + lrow;
#pragma unroll
        for (int es = 0; es < 8; ++es) {
          float o = oacc[rs][es][r] + lO[wr * 4224 + lrow * 132 + es * 16 + ln];
          Zs[(long)srow * (NHEAD * EMBED) + h * EMBED + es * 16 + ln] = f2b(o * rl);
        }
      }
  }
}

// ---------------- out = Zs · proj, split-K=8 into partials ----------------
__global__ __launch_bounds__(256, 2) void final_gemm_kernel(const u16* __restrict__ Zs,
                                                            const u16* __restrict__ projT,
                                                            float* __restrict__ pbuf) {
  const int t = blockIdx.x;   // m-tile 0..15
  const int kc = blockIdx.y;  // k-chunk 0..7 (256 wide)
  gemm128<float>(Zs + (long)t * 128 * (NHEAD * EMBED) + kc * 256, projT + kc * 256,
                 pbuf + (long)kc * SEQ * EMBED + t * 128 * EMBED,
                 NHEAD * EMBED, NHEAD * EMBED, EMBED, 4, nullptr, nullptr, 1.f);
}

__global__ __launch_bounds__(256) void reduce_kernel(const float* __restrict__ pbuf,
                                                     float* __restrict__ out) {
  int i = (blockIdx.x * 256 + threadIdx.x) * 4;
  float4 s = {0.f, 0.f, 0.f, 0.f};
#pragma unroll
  for (int kc = 0; kc < 8; ++kc) {
    float4 v = *(const float4*)(pbuf + (long)kc * SEQ * EMBED + i);
    s.x += v.x; s.y += v.y; s.z += v.z; s.w += v.w;
  }
  *(float4*)(out + i) = s;
}

extern "C" void kernel_launch(void* const* d_in, const int* in_sizes, int n_in,
                              void* d_out, int out_size, void* d_ws, size_t ws_size,
                              hipStream_t stream) {
  const float* x    = (const float*)d_in[0];
  const float* Wq   = (const float*)d_in[1];
  const float* bq   = (const float*)d_in[2];
  const float* Wk   = (const float*)d_in[3];
  const float* bk   = (const float*)d_in[4];
  const float* Wv   = (const float*)d_in[5];
  const float* bv   = (const float*)d_in[6];
  const float* proj = (const float*)d_in[7];
  float* out = (float*)d_out;

  char* ws = (char*)d_ws;
  // workspace layout (MiB offsets): total 52 MiB.
  // pbuf (8 MiB fp32 partials) aliases xb+Wqt, which are dead after qkv_gemm.
  u16* xb    = (u16*)(ws);                      // 2048x1024 bf16       (4 MiB)
  u16* Wqt   = (u16*)(ws + (4L << 20));         // [16][128][1024]      (4 MiB)
  u16* Wkt   = (u16*)(ws + (8L << 20));         //                      (4 MiB)
  u16* Wvt   = (u16*)(ws + (12L << 20));        //                      (4 MiB)
  u16* projT = (u16*)(ws + (16L << 20));        // [128][2048]          (0.5 MiB)
  u16* Qm    = (u16*)(ws + (17L << 20));        // [16][2048][128]      (8 MiB)
  u16* Km    = (u16*)(ws + (26L << 20));        // [16][2048][128]      (8 MiB)
  u16* Vt    = (u16*)(ws + (35L << 20));        // [16][128][2048]      (8 MiB)
  u16* Zs    = (u16*)(ws + (44L << 20));        // [2048][2048]         (8 MiB)
  float* pbuf = (float*)(ws);                   // [8][2048][128] fp32  (8 MiB, aliased)

  cast_x_kernel<<<dim3(SEQ * WORD / 1024), dim3(256), 0, stream>>>(x, xb);
  // one batched dispatch for all three weight transposes (z = 3*16 heads)
  transpose_cast_kernel<<<dim3(WORD / 32, EMBED / 32, 48), dim3(256), 0, stream>>>(
      Wq, Wk, Wv, Wqt, Wkt, Wvt, WORD, EMBED, (long)WORD * EMBED, 1);
  transpose_cast_kernel<<<dim3(SEQ / 32, EMBED / 32, 1), dim3(256), 0, stream>>>(
      proj, nullptr, nullptr, projT, nullptr, nullptr, SEQ, EMBED, 0, 0);

  qkv_gemm_kernel<<<dim3(16, NHEAD, 3), dim3(256), 0, stream>>>(
      xb, Wqt, Wkt, Wvt, bq, bk, bv, Qm, Km, Vt);

  attn_kernel<<<dim3(256), dim3(512), 0, stream>>>(Qm, Km, Vt, Zs);

  final_gemm_kernel<<<dim3(16, 8), dim3(256), 0, stream>>>(Zs, projT, pbuf);
  reduce_kernel<<<dim3(SEQ * EMBED / 1024), dim3(256), 0, stream>>>(pbuf, out);
}

// Round 5
// 184.208 us; speedup vs baseline: 1.2423x; 1.2423x over previous
//
#include <hip/hip_runtime.h>
#include <stdint.h>

#define GAS __attribute__((address_space(1)))
#define LAS __attribute__((address_space(3)))

typedef unsigned short u16;
typedef __attribute__((ext_vector_type(8))) __bf16 bf16x8;
typedef __attribute__((ext_vector_type(4))) float f32x4;
typedef __attribute__((ext_vector_type(2))) unsigned int u32x2;
typedef __attribute__((ext_vector_type(4))) unsigned int u32x4;

#define SEQ 2048
#define WORD 1024
#define EMBED 128
#define NHEAD 16

__device__ __forceinline__ u16 f2b(float f) {
  return __builtin_bit_cast(u16, (__bf16)f);
}

__device__ __forceinline__ unsigned cvt_pk_bf16(float lo, float hi) {
  unsigned r;
  asm("v_cvt_pk_bf16_f32 %0, %1, %2" : "=v"(r) : "v"(lo), "v"(hi));
  return r;
}

// ---------------- cast x (fp32 -> bf16), 4 elems/thread ----------------
__global__ __launch_bounds__(256) void cast_x_kernel(const float* __restrict__ x,
                                                     u16* __restrict__ xb) {
  int i = (blockIdx.x * 256 + threadIdx.x) * 4;
  float4 v = *(const float4*)(x + i);
  ushort4 o;
  o.x = f2b(v.x); o.y = f2b(v.y); o.z = f2b(v.z); o.w = f2b(v.w);
  *(ushort4*)(xb + i) = o;
}

// ------------- transpose+cast: src[R][C] fp32 -> dst[C][R] bf16 --------
// zsel: 0 -> plain (proj). 1 -> batched QKV weights (z selects W and head).
__global__ __launch_bounds__(256) void transpose_cast_kernel(
    const float* __restrict__ s0, const float* __restrict__ s1,
    const float* __restrict__ s2, u16* __restrict__ d0, u16* __restrict__ d1,
    u16* __restrict__ d2, int R, int C, long stride, int zsel) {
  __shared__ float tile[32][33];
  const float* s;
  u16* d;
  if (zsel) {
    int z = blockIdx.z;
    int wsel = z >> 4, hh = z & 15;
    s = (wsel == 0 ? s0 : wsel == 1 ? s1 : s2) + (long)hh * stride;
    d = (wsel == 0 ? d0 : wsel == 1 ? d1 : d2) + (long)hh * stride;
  } else {
    s = s0; d = d0;
  }
  int r0 = blockIdx.x * 32, c0 = blockIdx.y * 32;
  int tx = threadIdx.x & 31, ty = threadIdx.x >> 5;  // ty 0..7
#pragma unroll
  for (int i = 0; i < 4; ++i)
    tile[ty + i * 8][tx] = s[(long)(r0 + ty + i * 8) * C + c0 + tx];
  __syncthreads();
#pragma unroll
  for (int i = 0; i < 4; ++i)
    d[(long)(c0 + ty + i * 8) * R + r0 + tx] = f2b(tile[tx][ty + i * 8]);
}

// ---------------- generic 128x128-tile GEMM: C = (A·B^T + bias) * scale ----
// A: [*, lda] k-contiguous (tile rows), B: [*, ldb] k-contiguous (tile cols).
// BK=64, XOR-swizzled LDS (chunk c -> c ^ (r&7)), global_load_lds width 16.
template <typename OUT>
__device__ __forceinline__ void gemm128(const u16* __restrict__ A, const u16* __restrict__ B,
                                        OUT* __restrict__ C, int lda, int ldb, int ldc,
                                        int ksteps, const float* biasN, const float* biasM,
                                        float scale) {
  __shared__ u16 lA[128 * 64];
  __shared__ u16 lB[128 * 64];
  const int tid = threadIdx.x;
  const int l = tid & 63, w = tid >> 6;
  const int quad = l >> 4, ln = l & 15;
  const int wm = w >> 1, wn = w & 1;
  f32x4 acc[4][4] = {};
  for (int ks = 0; ks < ksteps; ++ks) {
    const u16* Ak = A + ks * 64;
    const u16* Bk = B + ks * 64;
    __syncthreads();  // prior-iter LDS reads complete before overwrite
#pragma unroll
    for (int i = 0; i < 4; ++i) {
      int idx = w * 256 + i * 64 + l;        // 16B-chunk index 0..1023
      int r = idx >> 3, cp = idx & 7;
      int cg = cp ^ (r & 7);                 // global chunk for this LDS slot
      __builtin_amdgcn_global_load_lds((const GAS void*)(Ak + (long)r * lda + cg * 8),
                                       (LAS void*)(lA + (w * 256 + i * 64) * 8), 16, 0, 0);
      __builtin_amdgcn_global_load_lds((const GAS void*)(Bk + (long)r * ldb + cg * 8),
                                       (LAS void*)(lB + (w * 256 + i * 64) * 8), 16, 0, 0);
    }
    __syncthreads();
    bf16x8 af[2][4], bfv[2][4];
#pragma unroll
    for (int kc = 0; kc < 2; ++kc) {
#pragma unroll
      for (int i = 0; i < 4; ++i) {
        int c = kc * 4 + quad;
        int rm = wm * 64 + i * 16 + ln;
        af[kc][i] = *(const bf16x8*)(lA + rm * 64 + ((c ^ (rm & 7)) * 8));
        int rn = wn * 64 + i * 16 + ln;
        bfv[kc][i] = *(const bf16x8*)(lB + rn * 64 + ((c ^ (rn & 7)) * 8));
      }
    }
#pragma unroll
    for (int kc = 0; kc < 2; ++kc)
#pragma unroll
      for (int i = 0; i < 4; ++i)
#pragma unroll
        for (int j = 0; j < 4; ++j)
          acc[i][j] = __builtin_amdgcn_mfma_f32_16x16x32_bf16(af[kc][i], bfv[kc][j],
                                                              acc[i][j], 0, 0, 0);
  }
  // epilogue: C row = wm*64+i*16+quad*4+reg, col = wn*64+j*16+ln (m89 C-layout)
#pragma unroll
  for (int i = 0; i < 4; ++i) {
#pragma unroll
    for (int j = 0; j < 4; ++j) {
      int row0 = wm * 64 + i * 16 + quad * 4;
      int col = wn * 64 + j * 16 + ln;
      float bn = biasN ? biasN[col] : 0.f;
#pragma unroll
      for (int reg = 0; reg < 4; ++reg) {
        int row = row0 + reg;
        float bm = biasM ? biasM[row] : 0.f;
        float v = (acc[i][j][reg] + bn + bm) * scale;
        if constexpr (sizeof(OUT) == 2)
          C[(long)row * ldc + col] = (OUT)f2b(v);
        else
          C[(long)row * ldc + col] = v;
      }
    }
  }
}

// ---------------- fused QKV projection (z: 0=Q,1=K,2=V^T) ----------------
// Q gets log2(e)/sqrt(E) folded in so attention can use exp2 directly.
__global__ __launch_bounds__(256, 3) void qkv_gemm_kernel(
    const u16* __restrict__ xb, const u16* __restrict__ Wqt, const u16* __restrict__ Wkt,
    const u16* __restrict__ Wvt, const float* __restrict__ bq, const float* __restrict__ bk,
    const float* __restrict__ bv, u16* __restrict__ Q, u16* __restrict__ Kb,
    u16* __restrict__ Vt) {
  const int t = blockIdx.x;   // tile index (m-tile for Q/K, n-tile for V)
  const int h = blockIdx.y;
  const int which = blockIdx.z;
  const float qscale = 0.12753042123789493f;  // log2(e)/sqrt(128)
  if (which == 0) {
    gemm128<u16>(xb + t * 128 * WORD, Wqt + h * EMBED * WORD,
                 Q + h * SEQ * EMBED + t * 128 * EMBED, WORD, WORD, EMBED,
                 WORD / 64, bq + h * EMBED, nullptr, qscale);
  } else if (which == 1) {
    gemm128<u16>(xb + t * 128 * WORD, Wkt + h * EMBED * WORD,
                 Kb + h * SEQ * EMBED + t * 128 * EMBED, WORD, WORD, EMBED,
                 WORD / 64, bk + h * EMBED, nullptr, 1.f);
  } else {
    // V^T[e][s] = sum_w Wvt[h][e][w] * x[s][w]  (A=Wvt rows e, B=x rows s)
    gemm128<u16>(Wvt + h * EMBED * WORD, xb + t * 128 * WORD,
                 Vt + h * EMBED * SEQ + t * 128, WORD, WORD, SEQ,
                 WORD / 64, nullptr, bv + h * EMBED, 1.f);
  }
}

// ---------------- flash attention v6: R2 structure + in-register softmax ----
// R4 post-mortem: V-from-global regressed (scattered 16B/lane loads, latency
// exposed); V returns to the LDS double buffer (R2's 60.4 µs structure).
// Keep R4's harness-validated pieces: swapped QK^T (S^T = mfma(K,Q), lane owns
// its q-row), in-register exp2 + rowsum, cvt_pk+permlane PA assembly (no P
// LDS round-trip, no ones-MFMA, zero bank conflicts), srl merge epilogue.
// Schedule: counted vmcnt(8) double-buffer, 2 raw barriers/superiter.
__global__ __launch_bounds__(512, 2) void attn_kernel(const u16* __restrict__ Q,
                                                      const u16* __restrict__ K,
                                                      const u16* __restrict__ V,  // V^T [h][e][s]
                                                      u16* __restrict__ Zs) {
  __shared__ __align__(16) u16 lKV[2][32768];  // per buf: Ke|Ko (32K) Ve|Vo (32K)
  const int bid = blockIdx.x;
  const int swz = (bid & 7) * 32 + (bid >> 3);  // bijective, 2 heads per XCD
  const int h = swz >> 4, qb = swz & 15;        // qb: 128-row tile, 0..15
  const int tid = threadIdx.x;
  const int l = tid & 63, w = tid >> 6, quad = l >> 4, ln = l & 15;
  const int wr = w >> 1, wk = w & 1;            // row-group / key-group
  const u16* Qh = Q + h * SEQ * EMBED;
  const u16* Kh = K + h * SEQ * EMBED;
  const u16* Vh = V + h * EMBED * SEQ;
  const int q0 = qb * 128 + wr * 32;

  // cooperative stage of one 128-key K+V superiter (64 KB) into lKV[buf]
  auto stage = [&](int buf, int sup) {
#pragma unroll
    for (int j = 0; j < 4; ++j) {
      int kb = j >> 1;                      // 0 = even 64-key tile, 1 = odd
      int cb = (j & 1) * 512 + w * 64;      // wave-uniform chunk base 0..1023
      int c = cb + l;
      int rk = c >> 4, cgk = (c & 15) ^ (rk & 15);
      __builtin_amdgcn_global_load_lds(
          (const GAS void*)(Kh + (sup * 128 + kb * 64 + rk) * EMBED + cgk * 8),
          (LAS void*)(&lKV[buf][kb * 8192 + cb * 8]), 16, 0, 0);
      int rv = c >> 3, cgv = (c & 7) ^ (rv & 7);
      __builtin_amdgcn_global_load_lds(
          (const GAS void*)(Vh + rv * SEQ + sup * 128 + kb * 64 + cgv * 8),
          (LAS void*)(&lKV[buf][16384 + kb * 8192 + cb * 8]), 16, 0, 0);
    }
  };

  // Q fragments in registers (frag layout: m/n=ln, k=quad*8+j); log2e/sqrt(E) folded
  bf16x8 qf[2][4];
#pragma unroll
  for (int rs = 0; rs < 2; ++rs)
#pragma unroll
    for (int kc = 0; kc < 4; ++kc)
      qf[rs][kc] = *(const bf16x8*)(Qh + (q0 + rs * 16 + ln) * EMBED + kc * 32 + quad * 8);

  f32x4 oacc[2][8] = {};
  float rsum[2] = {0.f, 0.f};

  stage(0, 0);  // prologue: 8 gll in flight

  int cur = 0;
#pragma unroll 1
  for (int sup = 0; sup < SEQ / 128; ++sup) {
    if (sup + 1 < SEQ / 128) {
      stage(cur ^ 1, sup + 1);
      asm volatile("s_waitcnt vmcnt(8)" ::: "memory");  // stage(sup) retired
    } else {
      asm volatile("s_waitcnt vmcnt(0)" ::: "memory");
    }
    __builtin_amdgcn_s_barrier();       // all waves' stage(sup) visible
    __builtin_amdgcn_sched_barrier(0);  // no ds_read hoisted above this point

    const u16* myK = &lKV[cur][wk * 8192];
    const u16* myV = &lKV[cur][16384 + wk * 8192];

    // ---- S^T = K'.Q (swapped): lane holds P[key=ns*16+quad*4+r][q=rs*16+ln] --
    f32x4 sacc[2][4] = {};
#pragma unroll
    for (int kc = 0; kc < 4; ++kc) {
      bf16x8 kf[4];
#pragma unroll
      for (int ns = 0; ns < 4; ++ns) {
        int kr = ns * 16 + ln;
        kf[ns] = *(const bf16x8*)(myK + kr * 128 + (((kc * 4 + quad) ^ (kr & 15)) * 8));
      }
      __builtin_amdgcn_s_setprio(1);
#pragma unroll
      for (int ns = 0; ns < 4; ++ns)
#pragma unroll
        for (int rs = 0; rs < 2; ++rs)
          sacc[rs][ns] = __builtin_amdgcn_mfma_f32_16x16x32_bf16(kf[ns], qf[rs][kc],
                                                                 sacc[rs][ns], 0, 0, 0);
      __builtin_amdgcn_s_setprio(0);
    }
    // ---- preload all V fragments from LDS (B-frag: n=e-row, k=key) ----
    bf16x8 vf[2][8];
#pragma unroll
    for (int kc = 0; kc < 2; ++kc)
#pragma unroll
      for (int es = 0; es < 8; ++es) {
        int er = es * 16 + ln;
        vf[kc][es] = *(const bf16x8*)(myV + er * 64 + (((kc * 4 + quad) ^ (er & 7)) * 8));
      }
    // ---- softmax + PA assembly + PV, fully in-register (validated R4) ----
#pragma unroll
    for (int rs = 0; rs < 2; ++rs) {
      float p[4][4];
#pragma unroll
      for (int ns = 0; ns < 4; ++ns)
#pragma unroll
        for (int r = 0; r < 4; ++r) p[ns][r] = exp2f(sacc[rs][ns][r]);
      float s0 = (p[0][0] + p[0][1]) + (p[0][2] + p[0][3]);
      float s1 = (p[1][0] + p[1][1]) + (p[1][2] + p[1][3]);
      float s2 = (p[2][0] + p[2][1]) + (p[2][2] + p[2][3]);
      float s3 = (p[3][0] + p[3][1]) + (p[3][2] + p[3][3]);
      rsum[rs] += (s0 + s1) + (s2 + s3);
#pragma unroll
      for (int kc = 0; kc < 2; ++kc) {
        // ns0 = kc*2 ("a" = keys [kc*32, kc*32+16)), ns1 = kc*2+1 ("b").
        // t = permlane32_swap(a, b); u = permlane16_swap(t.x, t.y):
        // u.x = [a@q0,a@q2,b@q0,b@q2], u.y = [a@q1,a@q3,b@q1,b@q3].
        int n0 = kc * 2, n1 = kc * 2 + 1;
        unsigned a0 = cvt_pk_bf16(p[n0][0], p[n0][1]);
        unsigned a1 = cvt_pk_bf16(p[n0][2], p[n0][3]);
        unsigned b0 = cvt_pk_bf16(p[n1][0], p[n1][1]);
        unsigned b1 = cvt_pk_bf16(p[n1][2], p[n1][3]);
        u32x2 t0 = __builtin_amdgcn_permlane32_swap(a0, b0, false, false);
        u32x2 u0 = __builtin_amdgcn_permlane16_swap(t0.x, t0.y, false, false);
        u32x2 t1 = __builtin_amdgcn_permlane32_swap(a1, b1, false, false);
        u32x2 u1 = __builtin_amdgcn_permlane16_swap(t1.x, t1.y, false, false);
        u32x4 paw = {u0.x, u1.x, u0.y, u1.y};
        bf16x8 pa = __builtin_bit_cast(bf16x8, paw);
        __builtin_amdgcn_s_setprio(1);
#pragma unroll
        for (int es = 0; es < 8; ++es)
          oacc[rs][es] = __builtin_amdgcn_mfma_f32_16x16x32_bf16(pa, vf[kc][es],
                                                                 oacc[rs][es], 0, 0, 0);
        __builtin_amdgcn_s_setprio(0);
      }
    }
    __builtin_amdgcn_sched_barrier(0);
    __builtin_amdgcn_s_barrier();  // all waves done reading lKV[cur]
    cur ^= 1;
  }

  // ---- rowsum: reduce over quads (q=ln), broadcast to oacc row alignment ----
  float srl[2][4];
#pragma unroll
  for (int rs = 0; rs < 2; ++rs) {
    float t = rsum[rs] + __shfl(rsum[rs], l ^ 16);
    t = t + __shfl(t, l ^ 32);
#pragma unroll
    for (int r = 0; r < 4; ++r) srl[rs][r] = __shfl(t, quad * 4 + r);
  }

  // ---- merge wk=1 into wk=0 via LDS (reuses lKV), divide by l, store ----
  __syncthreads();
  float* lO = (float*)lKV;  // [wr][32][132] fp32, wr 0..3 -> 67.6 KB
  if (wk == 1) {
#pragma unroll
    for (int rs = 0; rs < 2; ++rs) {
#pragma unroll
      for (int es = 0; es < 8; ++es)
#pragma unroll
        for (int r = 0; r < 4; ++r)
          lO[wr * 4224 + (rs * 16 + quad * 4 + r) * 132 + es * 16 + ln] = oacc[rs][es][r];
      if (ln == 0)
#pragma unroll
        for (int r = 0; r < 4; ++r)
          lO[wr * 4224 + (rs * 16 + quad * 4 + r) * 132 + 128] = srl[rs][r];
    }
  }
  __syncthreads();
  if (wk == 0) {
#pragma unroll
    for (int rs = 0; rs < 2; ++rs)
#pragma unroll
      for (int r = 0; r < 4; ++r) {
        int lrow = rs * 16 + quad * 4 + r;
        float lsum = srl[rs][r] + lO[wr * 4224 + lrow * 132 + 128];
        float rl = 1.f / lsum;
        int srow = q0 + lrow;
#pragma unroll
        for (int es = 0; es < 8; ++es) {
          float o = oacc[rs][es][r] + lO[wr * 4224 + lrow * 132 + es * 16 + ln];
          Zs[(long)srow * (NHEAD * EMBED) + h * EMBED + es * 16 + ln] = f2b(o * rl);
        }
      }
  }
}

// ---------------- out = Zs · proj, split-K=8 into partials ----------------
__global__ __launch_bounds__(256, 2) void final_gemm_kernel(const u16* __restrict__ Zs,
                                                            const u16* __restrict__ projT,
                                                            float* __restrict__ pbuf) {
  const int t = blockIdx.x;   // m-tile 0..15
  const int kc = blockIdx.y;  // k-chunk 0..7 (256 wide)
  gemm128<float>(Zs + (long)t * 128 * (NHEAD * EMBED) + kc * 256, projT + kc * 256,
                 pbuf + (long)kc * SEQ * EMBED + t * 128 * EMBED,
                 NHEAD * EMBED, NHEAD * EMBED, EMBED, 4, nullptr, nullptr, 1.f);
}

__global__ __launch_bounds__(256) void reduce_kernel(const float* __restrict__ pbuf,
                                                     float* __restrict__ out) {
  int i = (blockIdx.x * 256 + threadIdx.x) * 4;
  float4 s = {0.f, 0.f, 0.f, 0.f};
#pragma unroll
  for (int kc = 0; kc < 8; ++kc) {
    float4 v = *(const float4*)(pbuf + (long)kc * SEQ * EMBED + i);
    s.x += v.x; s.y += v.y; s.z += v.z; s.w += v.w;
  }
  *(float4*)(out + i) = s;
}

extern "C" void kernel_launch(void* const* d_in, const int* in_sizes, int n_in,
                              void* d_out, int out_size, void* d_ws, size_t ws_size,
                              hipStream_t stream) {
  const float* x    = (const float*)d_in[0];
  const float* Wq   = (const float*)d_in[1];
  const float* bq   = (const float*)d_in[2];
  const float* Wk   = (const float*)d_in[3];
  const float* bk   = (const float*)d_in[4];
  const float* Wv   = (const float*)d_in[5];
  const float* bv   = (const float*)d_in[6];
  const float* proj = (const float*)d_in[7];
  float* out = (float*)d_out;

  char* ws = (char*)d_ws;
  // workspace layout (MiB offsets): total 52 MiB.
  // pbuf (8 MiB fp32 partials) aliases xb+Wqt, which are dead after qkv_gemm.
  u16* xb    = (u16*)(ws);                      // 2048x1024 bf16       (4 MiB)
  u16* Wqt   = (u16*)(ws + (4L << 20));         // [16][128][1024]      (4 MiB)
  u16* Wkt   = (u16*)(ws + (8L << 20));         //                      (4 MiB)
  u16* Wvt   = (u16*)(ws + (12L << 20));        //                      (4 MiB)
  u16* projT = (u16*)(ws + (16L << 20));        // [128][2048]          (0.5 MiB)
  u16* Qm    = (u16*)(ws + (17L << 20));        // [16][2048][128]      (8 MiB)
  u16* Km    = (u16*)(ws + (26L << 20));        // [16][2048][128]      (8 MiB)
  u16* Vt    = (u16*)(ws + (35L << 20));        // [16][128][2048]      (8 MiB)
  u16* Zs    = (u16*)(ws + (44L << 20));        // [2048][2048]         (8 MiB)
  float* pbuf = (float*)(ws);                   // [8][2048][128] fp32  (8 MiB, aliased)

  cast_x_kernel<<<dim3(SEQ * WORD / 1024), dim3(256), 0, stream>>>(x, xb);
  // one batched dispatch for all three weight transposes (z = 3*16 heads)
  transpose_cast_kernel<<<dim3(WORD / 32, EMBED / 32, 48), dim3(256), 0, stream>>>(
      Wq, Wk, Wv, Wqt, Wkt, Wvt, WORD, EMBED, (long)WORD * EMBED, 1);
  transpose_cast_kernel<<<dim3(SEQ / 32, EMBED / 32, 1), dim3(256), 0, stream>>>(
      proj, nullptr, nullptr, projT, nullptr, nullptr, SEQ, EMBED, 0, 0);

  qkv_gemm_kernel<<<dim3(16, NHEAD, 3), dim3(256), 0, stream>>>(
      xb, Wqt, Wkt, Wvt, bq, bk, bv, Qm, Km, Vt);

  attn_kernel<<<dim3(256), dim3(512), 0, stream>>>(Qm, Km, Vt, Zs);

  final_gemm_kernel<<<dim3(16, 8), dim3(256), 0, stream>>>(Zs, projT, pbuf);
  reduce_kernel<<<dim3(SEQ * EMBED / 1024), dim3(256), 0, stream>>>(pbuf, out);
}

// Round 6
// 184.028 us; speedup vs baseline: 1.2435x; 1.0010x over previous
//
#include <hip/hip_runtime.h>
#include <stdint.h>

#define GAS __attribute__((address_space(1)))
#define LAS __attribute__((address_space(3)))

typedef unsigned short u16;
typedef __attribute__((ext_vector_type(8))) __bf16 bf16x8;
typedef __attribute__((ext_vector_type(4))) float f32x4;
typedef __attribute__((ext_vector_type(2))) unsigned int u32x2;
typedef __attribute__((ext_vector_type(4))) unsigned int u32x4;

#define SEQ 2048
#define WORD 1024
#define EMBED 128
#define NHEAD 16

__device__ __forceinline__ u16 f2b(float f) {
  return __builtin_bit_cast(u16, (__bf16)f);
}

__device__ __forceinline__ unsigned cvt_pk_bf16(float lo, float hi) {
  unsigned r;
  asm("v_cvt_pk_bf16_f32 %0, %1, %2" : "=v"(r) : "v"(lo), "v"(hi));
  return r;
}

// ---------------- cast x (fp32 -> bf16), 4 elems/thread ----------------
__global__ __launch_bounds__(256) void cast_x_kernel(const float* __restrict__ x,
                                                     u16* __restrict__ xb) {
  int i = (blockIdx.x * 256 + threadIdx.x) * 4;
  float4 v = *(const float4*)(x + i);
  ushort4 o;
  o.x = f2b(v.x); o.y = f2b(v.y); o.z = f2b(v.z); o.w = f2b(v.w);
  *(ushort4*)(xb + i) = o;
}

// ------------- transpose+cast: src[R][C] fp32 -> dst[C][R] bf16 --------
// zsel: 0 -> plain (proj). 1 -> batched QKV weights (z selects W and head).
__global__ __launch_bounds__(256) void transpose_cast_kernel(
    const float* __restrict__ s0, const float* __restrict__ s1,
    const float* __restrict__ s2, u16* __restrict__ d0, u16* __restrict__ d1,
    u16* __restrict__ d2, int R, int C, long stride, int zsel) {
  __shared__ float tile[32][33];
  const float* s;
  u16* d;
  if (zsel) {
    int z = blockIdx.z;
    int wsel = z >> 4, hh = z & 15;
    s = (wsel == 0 ? s0 : wsel == 1 ? s1 : s2) + (long)hh * stride;
    d = (wsel == 0 ? d0 : wsel == 1 ? d1 : d2) + (long)hh * stride;
  } else {
    s = s0; d = d0;
  }
  int r0 = blockIdx.x * 32, c0 = blockIdx.y * 32;
  int tx = threadIdx.x & 31, ty = threadIdx.x >> 5;  // ty 0..7
#pragma unroll
  for (int i = 0; i < 4; ++i)
    tile[ty + i * 8][tx] = s[(long)(r0 + ty + i * 8) * C + c0 + tx];
  __syncthreads();
#pragma unroll
  for (int i = 0; i < 4; ++i)
    d[(long)(c0 + ty + i * 8) * R + r0 + tx] = f2b(tile[tx][ty + i * 8]);
}

// ---------------- generic 128x128-tile GEMM: C = (A·B^T + bias) * scale ----
// A: [*, lda] k-contiguous (tile rows), B: [*, ldb] k-contiguous (tile cols).
// BK=64, XOR-swizzled LDS (chunk c -> c ^ (r&7)), global_load_lds width 16.
template <typename OUT>
__device__ __forceinline__ void gemm128(const u16* __restrict__ A, const u16* __restrict__ B,
                                        OUT* __restrict__ C, int lda, int ldb, int ldc,
                                        int ksteps, const float* biasN, const float* biasM,
                                        float scale) {
  __shared__ u16 lA[128 * 64];
  __shared__ u16 lB[128 * 64];
  const int tid = threadIdx.x;
  const int l = tid & 63, w = tid >> 6;
  const int quad = l >> 4, ln = l & 15;
  const int wm = w >> 1, wn = w & 1;
  f32x4 acc[4][4] = {};
  for (int ks = 0; ks < ksteps; ++ks) {
    const u16* Ak = A + ks * 64;
    const u16* Bk = B + ks * 64;
    __syncthreads();  // prior-iter LDS reads complete before overwrite
#pragma unroll
    for (int i = 0; i < 4; ++i) {
      int idx = w * 256 + i * 64 + l;        // 16B-chunk index 0..1023
      int r = idx >> 3, cp = idx & 7;
      int cg = cp ^ (r & 7);                 // global chunk for this LDS slot
      __builtin_amdgcn_global_load_lds((const GAS void*)(Ak + (long)r * lda + cg * 8),
                                       (LAS void*)(lA + (w * 256 + i * 64) * 8), 16, 0, 0);
      __builtin_amdgcn_global_load_lds((const GAS void*)(Bk + (long)r * ldb + cg * 8),
                                       (LAS void*)(lB + (w * 256 + i * 64) * 8), 16, 0, 0);
    }
    __syncthreads();
    bf16x8 af[2][4], bfv[2][4];
#pragma unroll
    for (int kc = 0; kc < 2; ++kc) {
#pragma unroll
      for (int i = 0; i < 4; ++i) {
        int c = kc * 4 + quad;
        int rm = wm * 64 + i * 16 + ln;
        af[kc][i] = *(const bf16x8*)(lA + rm * 64 + ((c ^ (rm & 7)) * 8));
        int rn = wn * 64 + i * 16 + ln;
        bfv[kc][i] = *(const bf16x8*)(lB + rn * 64 + ((c ^ (rn & 7)) * 8));
      }
    }
#pragma unroll
    for (int kc = 0; kc < 2; ++kc)
#pragma unroll
      for (int i = 0; i < 4; ++i)
#pragma unroll
        for (int j = 0; j < 4; ++j)
          acc[i][j] = __builtin_amdgcn_mfma_f32_16x16x32_bf16(af[kc][i], bfv[kc][j],
                                                              acc[i][j], 0, 0, 0);
  }
  // epilogue: C row = wm*64+i*16+quad*4+reg, col = wn*64+j*16+ln (m89 C-layout)
#pragma unroll
  for (int i = 0; i < 4; ++i) {
#pragma unroll
    for (int j = 0; j < 4; ++j) {
      int row0 = wm * 64 + i * 16 + quad * 4;
      int col = wn * 64 + j * 16 + ln;
      float bn = biasN ? biasN[col] : 0.f;
#pragma unroll
      for (int reg = 0; reg < 4; ++reg) {
        int row = row0 + reg;
        float bm = biasM ? biasM[row] : 0.f;
        float v = (acc[i][j][reg] + bn + bm) * scale;
        if constexpr (sizeof(OUT) == 2)
          C[(long)row * ldc + col] = (OUT)f2b(v);
        else
          C[(long)row * ldc + col] = v;
      }
    }
  }
}

// ---------------- fused QKV projection (z: 0=Q,1=K,2=V^T) ----------------
// Q gets log2(e)/sqrt(E) folded in so attention can use exp2 directly.
__global__ __launch_bounds__(256, 3) void qkv_gemm_kernel(
    const u16* __restrict__ xb, const u16* __restrict__ Wqt, const u16* __restrict__ Wkt,
    const u16* __restrict__ Wvt, const float* __restrict__ bq, const float* __restrict__ bk,
    const float* __restrict__ bv, u16* __restrict__ Q, u16* __restrict__ Kb,
    u16* __restrict__ Vt) {
  const int t = blockIdx.x;   // tile index (m-tile for Q/K, n-tile for V)
  const int h = blockIdx.y;
  const int which = blockIdx.z;
  const float qscale = 0.12753042123789493f;  // log2(e)/sqrt(128)
  if (which == 0) {
    gemm128<u16>(xb + t * 128 * WORD, Wqt + h * EMBED * WORD,
                 Q + h * SEQ * EMBED + t * 128 * EMBED, WORD, WORD, EMBED,
                 WORD / 64, bq + h * EMBED, nullptr, qscale);
  } else if (which == 1) {
    gemm128<u16>(xb + t * 128 * WORD, Wkt + h * EMBED * WORD,
                 Kb + h * SEQ * EMBED + t * 128 * EMBED, WORD, WORD, EMBED,
                 WORD / 64, bk + h * EMBED, nullptr, 1.f);
  } else {
    // V^T[e][s] = sum_w Wvt[h][e][w] * x[s][w]  (A=Wvt rows e, B=x rows s)
    gemm128<u16>(Wvt + h * EMBED * WORD, xb + t * 128 * WORD,
                 Vt + h * EMBED * SEQ + t * 128, WORD, WORD, SEQ,
                 WORD / 64, nullptr, bv + h * EMBED, 1.f);
  }
}

// ---------------- flash attention v7: 2 blocks/CU for latency hiding ----
// R5 post-mortem: all pipes <40% busy, Occupancy 18.6% (1 block/CU, 2
// waves/SIMD) -> latency-bound. v7 halves the superiter (64 keys) so the
// K+V double buffer is 64 KB -> 2 blocks/CU (4 waves/SIMD). Grid 512
// blocks of 64 q-rows; each wave owns 16 q-rows (rs dim dropped), halving
// register state (fits __launch_bounds__(512,4) without spill).
// All validated R5 pieces carry over with one dimension removed: swapped
// QK^T, in-register exp2+rowsum, cvt_pk+permlane PA assembly, counted
// vmcnt (now 4), XCD swizzle (2 heads/XCD), merge epilogue.
__global__ __launch_bounds__(512, 4) void attn_kernel(const u16* __restrict__ Q,
                                                      const u16* __restrict__ K,
                                                      const u16* __restrict__ V,  // V^T [h][e][s]
                                                      u16* __restrict__ Zs) {
  __shared__ __align__(16) u16 lKV[2][16384];  // per buf: K 16 KB | V 16 KB
  const int bid = blockIdx.x;
  const int swz = (bid & 7) * 64 + (bid >> 3);  // bijective, 2 heads per XCD
  const int h = swz >> 5, qb = swz & 31;        // qb: 64-row tile, 0..31
  const int tid = threadIdx.x;
  const int l = tid & 63, w = tid >> 6, quad = l >> 4, ln = l & 15;
  const int wr = w >> 1, wk = w & 1;            // row-group 0..3 / key-group
  const u16* Qh = Q + h * SEQ * EMBED;
  const u16* Kh = K + h * SEQ * EMBED;
  const u16* Vh = V + h * EMBED * SEQ;
  const int q0 = qb * 64 + wr * 16;

  // cooperative stage of one 64-key K+V superiter (32 KB): 4 gll/wave.
  // K tile [64][128] (1024 16B-chunks), V^T tile [128][64] (1024 chunks).
  auto stage = [&](int buf, int sup) {
#pragma unroll
    for (int j = 0; j < 2; ++j) {
      int c = j * 512 + w * 64 + l;          // chunk 0..1023
      int rk = c >> 4, cgk = (c & 15) ^ (rk & 15);
      __builtin_amdgcn_global_load_lds(
          (const GAS void*)(Kh + (sup * 64 + rk) * EMBED + cgk * 8),
          (LAS void*)(&lKV[buf][c * 8]), 16, 0, 0);
      int rv = c >> 3, cgv = (c & 7) ^ (rv & 7);
      __builtin_amdgcn_global_load_lds(
          (const GAS void*)(Vh + (long)rv * SEQ + sup * 64 + cgv * 8),
          (LAS void*)(&lKV[buf][8192 + c * 8]), 16, 0, 0);
    }
  };

  // Q fragments (B-frag of swapped QK: n=ln=q-row, k=quad*8+j); log2e/sqrt(E) folded
  bf16x8 qf[4];
#pragma unroll
  for (int kc = 0; kc < 4; ++kc)
    qf[kc] = *(const bf16x8*)(Qh + (q0 + ln) * EMBED + kc * 32 + quad * 8);

  f32x4 oacc[8] = {};
  float rsum = 0.f;

  stage(0, 0);  // prologue: 4 gll in flight

  int cur = 0;
#pragma unroll 1
  for (int sup = 0; sup < SEQ / 64; ++sup) {
    if (sup + 1 < SEQ / 64) {
      stage(cur ^ 1, sup + 1);
      asm volatile("s_waitcnt vmcnt(4)" ::: "memory");  // stage(sup) retired
    } else {
      asm volatile("s_waitcnt vmcnt(0)" ::: "memory");
    }
    __builtin_amdgcn_s_barrier();       // all waves' stage(sup) visible
    __builtin_amdgcn_sched_barrier(0);  // no ds_read hoisted above this point

    const u16* myK = &lKV[cur][0];
    const u16* myV = &lKV[cur][8192];

    // ---- S^T = K'.Q (swapped): lane holds P[key=wk*32+ns*16+quad*4+r][q=ln] --
    f32x4 sacc[2] = {};
#pragma unroll
    for (int kc = 0; kc < 4; ++kc) {
      bf16x8 kf[2];
#pragma unroll
      for (int ns = 0; ns < 2; ++ns) {
        int kr = wk * 32 + ns * 16 + ln;
        kf[ns] = *(const bf16x8*)(myK + kr * 128 + (((kc * 4 + quad) ^ (kr & 15)) * 8));
      }
      __builtin_amdgcn_s_setprio(1);
#pragma unroll
      for (int ns = 0; ns < 2; ++ns)
        sacc[ns] = __builtin_amdgcn_mfma_f32_16x16x32_bf16(kf[ns], qf[kc], sacc[ns], 0, 0, 0);
      __builtin_amdgcn_s_setprio(0);
    }
    // ---- V fragments from LDS (B-frag: n=e-row, k=key in wave's 32-window) --
    bf16x8 vf[8];
#pragma unroll
    for (int es = 0; es < 8; ++es) {
      int er = es * 16 + ln;
      vf[es] = *(const bf16x8*)(myV + er * 64 + (((wk * 4 + quad) ^ (er & 7)) * 8));
    }
    // ---- softmax + PA assembly + PV, fully in-register ----
    float p[2][4];
#pragma unroll
    for (int ns = 0; ns < 2; ++ns)
#pragma unroll
      for (int r = 0; r < 4; ++r) p[ns][r] = exp2f(sacc[ns][r]);
    rsum += ((p[0][0] + p[0][1]) + (p[0][2] + p[0][3])) +
            ((p[1][0] + p[1][1]) + (p[1][2] + p[1][3]));
    // a = keys [0,16), b = keys [16,32) of the wave's window.
    // t = permlane32_swap(a, b); u = permlane16_swap(t.x, t.y):
    // u.x = [a@q0,a@q2,b@q0,b@q2], u.y = [a@q1,a@q3,b@q1,b@q3].
    {
      unsigned a0 = cvt_pk_bf16(p[0][0], p[0][1]);
      unsigned a1 = cvt_pk_bf16(p[0][2], p[0][3]);
      unsigned b0 = cvt_pk_bf16(p[1][0], p[1][1]);
      unsigned b1 = cvt_pk_bf16(p[1][2], p[1][3]);
      u32x2 t0 = __builtin_amdgcn_permlane32_swap(a0, b0, false, false);
      u32x2 u0 = __builtin_amdgcn_permlane16_swap(t0.x, t0.y, false, false);
      u32x2 t1 = __builtin_amdgcn_permlane32_swap(a1, b1, false, false);
      u32x2 u1 = __builtin_amdgcn_permlane16_swap(t1.x, t1.y, false, false);
      u32x4 paw = {u0.x, u1.x, u0.y, u1.y};
      bf16x8 pa = __builtin_bit_cast(bf16x8, paw);
      __builtin_amdgcn_s_setprio(1);
#pragma unroll
      for (int es = 0; es < 8; ++es)
        oacc[es] = __builtin_amdgcn_mfma_f32_16x16x32_bf16(pa, vf[es], oacc[es], 0, 0, 0);
      __builtin_amdgcn_s_setprio(0);
    }
    __builtin_amdgcn_sched_barrier(0);
    __builtin_amdgcn_s_barrier();  // all waves done reading lKV[cur]
    cur ^= 1;
  }

  // ---- rowsum: reduce over quads (q=ln), broadcast to oacc row alignment ----
  // t(lane ln) = full rowsum for q-row ln over this wave's keys; srl[r] is the
  // rowsum for the oacc row (quad*4+r) this lane stores.
  float t = rsum + __shfl(rsum, l ^ 16);
  t = t + __shfl(t, l ^ 32);
  float srl[4];
#pragma unroll
  for (int r = 0; r < 4; ++r) srl[r] = __shfl(t, quad * 4 + r);

  // ---- merge wk=1 into wk=0 via LDS (reuses lKV), divide by l, store ----
  __syncthreads();
  float* lO = (float*)lKV;  // [wr][16][132] fp32 = 33.8 KB
  if (wk == 1) {
#pragma unroll
    for (int es = 0; es < 8; ++es)
#pragma unroll
      for (int r = 0; r < 4; ++r)
        lO[wr * 2112 + (quad * 4 + r) * 132 + es * 16 + ln] = oacc[es][r];
    if (ln == 0)
#pragma unroll
      for (int r = 0; r < 4; ++r)
        lO[wr * 2112 + (quad * 4 + r) * 132 + 128] = srl[r];
  }
  __syncthreads();
  if (wk == 0) {
#pragma unroll
    for (int r = 0; r < 4; ++r) {
      int lrow = quad * 4 + r;
      float lsum = srl[r] + lO[wr * 2112 + lrow * 132 + 128];
      float rl = 1.f / lsum;
      int srow = q0 + lrow;
#pragma unroll
      for (int es = 0; es < 8; ++es) {
        float o = oacc[es][r] + lO[wr * 2112 + lrow * 132 + es * 16 + ln];
        Zs[(long)srow * (NHEAD * EMBED) + h * EMBED + es * 16 + ln] = f2b(o * rl);
      }
    }
  }
}

// ---------------- out = Zs · proj, split-K=8 into partials ----------------
__global__ __launch_bounds__(256, 2) void final_gemm_kernel(const u16* __restrict__ Zs,
                                                            const u16* __restrict__ projT,
                                                            float* __restrict__ pbuf) {
  const int t = blockIdx.x;   // m-tile 0..15
  const int kc = blockIdx.y;  // k-chunk 0..7 (256 wide)
  gemm128<float>(Zs + (long)t * 128 * (NHEAD * EMBED) + kc * 256, projT + kc * 256,
                 pbuf + (long)kc * SEQ * EMBED + t * 128 * EMBED,
                 NHEAD * EMBED, NHEAD * EMBED, EMBED, 4, nullptr, nullptr, 1.f);
}

__global__ __launch_bounds__(256) void reduce_kernel(const float* __restrict__ pbuf,
                                                     float* __restrict__ out) {
  int i = (blockIdx.x * 256 + threadIdx.x) * 4;
  float4 s = {0.f, 0.f, 0.f, 0.f};
#pragma unroll
  for (int kc = 0; kc < 8; ++kc) {
    float4 v = *(const float4*)(pbuf + (long)kc * SEQ * EMBED + i);
    s.x += v.x; s.y += v.y; s.z += v.z; s.w += v.w;
  }
  *(float4*)(out + i) = s;
}

extern "C" void kernel_launch(void* const* d_in, const int* in_sizes, int n_in,
                              void* d_out, int out_size, void* d_ws, size_t ws_size,
                              hipStream_t stream) {
  const float* x    = (const float*)d_in[0];
  const float* Wq   = (const float*)d_in[1];
  const float* bq   = (const float*)d_in[2];
  const float* Wk   = (const float*)d_in[3];
  const float* bk   = (const float*)d_in[4];
  const float* Wv   = (const float*)d_in[5];
  const float* bv   = (const float*)d_in[6];
  const float* proj = (const float*)d_in[7];
  float* out = (float*)d_out;

  char* ws = (char*)d_ws;
  // workspace layout (MiB offsets): total 52 MiB.
  // pbuf (8 MiB fp32 partials) aliases xb+Wqt, which are dead after qkv_gemm.
  u16* xb    = (u16*)(ws);                      // 2048x1024 bf16       (4 MiB)
  u16* Wqt   = (u16*)(ws + (4L << 20));         // [16][128][1024]      (4 MiB)
  u16* Wkt   = (u16*)(ws + (8L << 20));         //                      (4 MiB)
  u16* Wvt   = (u16*)(ws + (12L << 20));        //                      (4 MiB)
  u16* projT = (u16*)(ws + (16L << 20));        // [128][2048]          (0.5 MiB)
  u16* Qm    = (u16*)(ws + (17L << 20));        // [16][2048][128]      (8 MiB)
  u16* Km    = (u16*)(ws + (26L << 20));        // [16][2048][128]      (8 MiB)
  u16* Vt    = (u16*)(ws + (35L << 20));        // [16][128][2048]      (8 MiB)
  u16* Zs    = (u16*)(ws + (44L << 20));        // [2048][2048]         (8 MiB)
  float* pbuf = (float*)(ws);                   // [8][2048][128] fp32  (8 MiB, aliased)

  cast_x_kernel<<<dim3(SEQ * WORD / 1024), dim3(256), 0, stream>>>(x, xb);
  // one batched dispatch for all three weight transposes (z = 3*16 heads)
  transpose_cast_kernel<<<dim3(WORD / 32, EMBED / 32, 48), dim3(256), 0, stream>>>(
      Wq, Wk, Wv, Wqt, Wkt, Wvt, WORD, EMBED, (long)WORD * EMBED, 1);
  transpose_cast_kernel<<<dim3(SEQ / 32, EMBED / 32, 1), dim3(256), 0, stream>>>(
      proj, nullptr, nullptr, projT, nullptr, nullptr, SEQ, EMBED, 0, 0);

  qkv_gemm_kernel<<<dim3(16, NHEAD, 3), dim3(256), 0, stream>>>(
      xb, Wqt, Wkt, Wvt, bq, bk, bv, Qm, Km, Vt);

  attn_kernel<<<dim3(512), dim3(512), 0, stream>>>(Qm, Km, Vt, Zs);

  final_gemm_kernel<<<dim3(16, 8), dim3(256), 0, stream>>>(Zs, projT, pbuf);
  reduce_kernel<<<dim3(SEQ * EMBED / 1024), dim3(256), 0, stream>>>(pbuf, out);
}

// Round 7
// 171.478 us; speedup vs baseline: 1.3345x; 1.0732x over previous
//
#include <hip/hip_runtime.h>
#include <stdint.h>

#define GAS __attribute__((address_space(1)))
#define LAS __attribute__((address_space(3)))

typedef unsigned short u16;
typedef __attribute__((ext_vector_type(8))) __bf16 bf16x8;
typedef __attribute__((ext_vector_type(4))) float f32x4;
typedef __attribute__((ext_vector_type(2))) unsigned int u32x2;
typedef __attribute__((ext_vector_type(4))) unsigned int u32x4;

#define SEQ 2048
#define WORD 1024
#define EMBED 128
#define NHEAD 16

__device__ __forceinline__ u16 f2b(float f) {
  return __builtin_bit_cast(u16, (__bf16)f);
}

__device__ __forceinline__ unsigned cvt_pk_bf16(float lo, float hi) {
  unsigned r;
  asm("v_cvt_pk_bf16_f32 %0, %1, %2" : "=v"(r) : "v"(lo), "v"(hi));
  return r;
}

// ---------------- fused prep: weight transposes + proj transpose + x cast ----
// 1-D grid, 6912 blocks of 256 thr:
//   [0,6144):   W{q,k,v} transpose+cast, z = bid>>7 (48 z), 32x4 tiles
//   [6144,6400): proj transpose+cast, 64x4 tiles
//   [6400,6912): x fp32->bf16 cast, 4096 elems/block
// Replaces 3 dispatches (cast_x + 2 transpose_cast) with 1 (gap removal).
__global__ __launch_bounds__(256) void prep_kernel(
    const float* __restrict__ x, const float* __restrict__ Wq,
    const float* __restrict__ Wk, const float* __restrict__ Wv,
    const float* __restrict__ proj, u16* __restrict__ xb, u16* __restrict__ Wqt,
    u16* __restrict__ Wkt, u16* __restrict__ Wvt, u16* __restrict__ projT) {
  __shared__ float tile[32][33];
  const int bid = blockIdx.x;
  const int tid = threadIdx.x;
  const int tx = tid & 31, ty = tid >> 5;  // ty 0..7
  if (bid < 6144) {
    int z = bid >> 7, xy = bid & 127;  // 128 blocks per z (32 x 4)
    int bx = xy & 31, by = xy >> 5;
    int wsel = z >> 4, hh = z & 15;
    const float* s = (wsel == 0 ? Wq : wsel == 1 ? Wk : Wv) + (long)hh * (WORD * EMBED);
    u16* d = (wsel == 0 ? Wqt : wsel == 1 ? Wkt : Wvt) + (long)hh * (WORD * EMBED);
    int r0 = bx * 32, c0 = by * 32;
#pragma unroll
    for (int i = 0; i < 4; ++i)
      tile[ty + i * 8][tx] = s[(long)(r0 + ty + i * 8) * EMBED + c0 + tx];
    __syncthreads();
#pragma unroll
    for (int i = 0; i < 4; ++i)
      d[(long)(c0 + ty + i * 8) * WORD + r0 + tx] = f2b(tile[tx][ty + i * 8]);
  } else if (bid < 6400) {
    int idx = bid - 6144;  // 0..255 (64 x 4)
    int bx = idx & 63, by = idx >> 6;
    int r0 = bx * 32, c0 = by * 32;
#pragma unroll
    for (int i = 0; i < 4; ++i)
      tile[ty + i * 8][tx] = proj[(long)(r0 + ty + i * 8) * EMBED + c0 + tx];
    __syncthreads();
#pragma unroll
    for (int i = 0; i < 4; ++i)
      projT[(long)(c0 + ty + i * 8) * SEQ + r0 + tx] = f2b(tile[tx][ty + i * 8]);
  } else {
    long base = (long)(bid - 6400) * 4096;  // 512 blocks x 4096 floats
#pragma unroll
    for (int k = 0; k < 4; ++k) {
      long i = base + k * 1024 + tid * 4;
      float4 v = *(const float4*)(x + i);
      ushort4 o;
      o.x = f2b(v.x); o.y = f2b(v.y); o.z = f2b(v.z); o.w = f2b(v.w);
      *(ushort4*)(xb + i) = o;
    }
  }
}

// ---------------- generic 128x128-tile GEMM: C = (A·B^T + bias) * scale ----
// A: [*, lda] k-contiguous (tile rows), B: [*, ldb] k-contiguous (tile cols).
// BK=64, XOR-swizzled LDS (chunk c -> c ^ (r&7)), global_load_lds width 16.
template <typename OUT>
__device__ __forceinline__ void gemm128(const u16* __restrict__ A, const u16* __restrict__ B,
                                        OUT* __restrict__ C, int lda, int ldb, int ldc,
                                        int ksteps, const float* biasN, const float* biasM,
                                        float scale) {
  __shared__ u16 lA[128 * 64];
  __shared__ u16 lB[128 * 64];
  const int tid = threadIdx.x;
  const int l = tid & 63, w = tid >> 6;
  const int quad = l >> 4, ln = l & 15;
  const int wm = w >> 1, wn = w & 1;
  f32x4 acc[4][4] = {};
  for (int ks = 0; ks < ksteps; ++ks) {
    const u16* Ak = A + ks * 64;
    const u16* Bk = B + ks * 64;
    __syncthreads();  // prior-iter LDS reads complete before overwrite
#pragma unroll
    for (int i = 0; i < 4; ++i) {
      int idx = w * 256 + i * 64 + l;        // 16B-chunk index 0..1023
      int r = idx >> 3, cp = idx & 7;
      int cg = cp ^ (r & 7);                 // global chunk for this LDS slot
      __builtin_amdgcn_global_load_lds((const GAS void*)(Ak + (long)r * lda + cg * 8),
                                       (LAS void*)(lA + (w * 256 + i * 64) * 8), 16, 0, 0);
      __builtin_amdgcn_global_load_lds((const GAS void*)(Bk + (long)r * ldb + cg * 8),
                                       (LAS void*)(lB + (w * 256 + i * 64) * 8), 16, 0, 0);
    }
    __syncthreads();
    bf16x8 af[2][4], bfv[2][4];
#pragma unroll
    for (int kc = 0; kc < 2; ++kc) {
#pragma unroll
      for (int i = 0; i < 4; ++i) {
        int c = kc * 4 + quad;
        int rm = wm * 64 + i * 16 + ln;
        af[kc][i] = *(const bf16x8*)(lA + rm * 64 + ((c ^ (rm & 7)) * 8));
        int rn = wn * 64 + i * 16 + ln;
        bfv[kc][i] = *(const bf16x8*)(lB + rn * 64 + ((c ^ (rn & 7)) * 8));
      }
    }
#pragma unroll
    for (int kc = 0; kc < 2; ++kc)
#pragma unroll
      for (int i = 0; i < 4; ++i)
#pragma unroll
        for (int j = 0; j < 4; ++j)
          acc[i][j] = __builtin_amdgcn_mfma_f32_16x16x32_bf16(af[kc][i], bfv[kc][j],
                                                              acc[i][j], 0, 0, 0);
  }
  // epilogue: C row = wm*64+i*16+quad*4+reg, col = wn*64+j*16+ln (m89 C-layout)
#pragma unroll
  for (int i = 0; i < 4; ++i) {
#pragma unroll
    for (int j = 0; j < 4; ++j) {
      int row0 = wm * 64 + i * 16 + quad * 4;
      int col = wn * 64 + j * 16 + ln;
      float bn = biasN ? biasN[col] : 0.f;
#pragma unroll
      for (int reg = 0; reg < 4; ++reg) {
        int row = row0 + reg;
        float bm = biasM ? biasM[row] : 0.f;
        float v = (acc[i][j][reg] + bn + bm) * scale;
        if constexpr (sizeof(OUT) == 2)
          C[(long)row * ldc + col] = (OUT)f2b(v);
        else
          C[(long)row * ldc + col] = v;
      }
    }
  }
}

// ---------------- fused QKV projection (z: 0=Q,1=K,2=V^T) ----------------
// Q gets log2(e)/sqrt(E) folded in so attention can use exp2 directly.
// Group-locality swizzle: linear bid remapped so each XCD owns 6 consecutive
// (h,which) groups (16 blocks each share a 256 KB weight slab) -> per-XCD L2
// weight working set 12 MB -> 5.5 MB. Bijective: 768 = 8 x 96.
__global__ __launch_bounds__(256, 3) void qkv_gemm_kernel(
    const u16* __restrict__ xb, const u16* __restrict__ Wqt, const u16* __restrict__ Wkt,
    const u16* __restrict__ Wvt, const float* __restrict__ bq, const float* __restrict__ bk,
    const float* __restrict__ bv, u16* __restrict__ Q, u16* __restrict__ Kb,
    u16* __restrict__ Vt) {
  const int lin = blockIdx.x + 16 * (blockIdx.y + 16 * blockIdx.z);
  const int s = (lin & 7) * 96 + (lin >> 3);
  const int t = s & 15;            // m-tile (n-tile for V)
  const int h = (s >> 4) & 15;
  const int which = s >> 8;
  const float qscale = 0.12753042123789493f;  // log2(e)/sqrt(128)
  if (which == 0) {
    gemm128<u16>(xb + t * 128 * WORD, Wqt + h * EMBED * WORD,
                 Q + h * SEQ * EMBED + t * 128 * EMBED, WORD, WORD, EMBED,
                 WORD / 64, bq + h * EMBED, nullptr, qscale);
  } else if (which == 1) {
    gemm128<u16>(xb + t * 128 * WORD, Wkt + h * EMBED * WORD,
                 Kb + h * SEQ * EMBED + t * 128 * EMBED, WORD, WORD, EMBED,
                 WORD / 64, bk + h * EMBED, nullptr, 1.f);
  } else {
    // V^T[e][s] = sum_w Wvt[h][e][w] * x[s][w]  (A=Wvt rows e, B=x rows s)
    gemm128<u16>(Wvt + h * EMBED * WORD, xb + t * 128 * WORD,
                 Vt + h * EMBED * SEQ + t * 128, WORD, WORD, SEQ,
                 WORD / 64, nullptr, bv + h * EMBED, 1.f);
  }
}

// ---------------- flash attention v6 (R5, proven 51.7 us): ----------------
// 8-wave blocks (4 row-groups x 2 key-groups), 128-key superiter, K+V LDS
// double buffer (128 KB), counted vmcnt(8), swapped QK^T with in-register
// exp2 + rowsum + cvt_pk/permlane PA assembly, XCD swizzle, merge epilogue.
// R6 lesson: do NOT shrink the superiter — per-superiter fixed overhead is
// ~400 cyc; 128-key tiles amortize it best at this LDS/occupancy point.
__global__ __launch_bounds__(512, 2) void attn_kernel(const u16* __restrict__ Q,
                                                      const u16* __restrict__ K,
                                                      const u16* __restrict__ V,  // V^T [h][e][s]
                                                      u16* __restrict__ Zs) {
  __shared__ __align__(16) u16 lKV[2][32768];  // per buf: Ke|Ko (32K) Ve|Vo (32K)
  const int bid = blockIdx.x;
  const int swz = (bid & 7) * 32 + (bid >> 3);  // bijective, 2 heads per XCD
  const int h = swz >> 4, qb = swz & 15;        // qb: 128-row tile, 0..15
  const int tid = threadIdx.x;
  const int l = tid & 63, w = tid >> 6, quad = l >> 4, ln = l & 15;
  const int wr = w >> 1, wk = w & 1;            // row-group / key-group
  const u16* Qh = Q + h * SEQ * EMBED;
  const u16* Kh = K + h * SEQ * EMBED;
  const u16* Vh = V + h * EMBED * SEQ;
  const int q0 = qb * 128 + wr * 32;

  // cooperative stage of one 128-key K+V superiter (64 KB) into lKV[buf]
  auto stage = [&](int buf, int sup) {
#pragma unroll
    for (int j = 0; j < 4; ++j) {
      int kb = j >> 1;                      // 0 = even 64-key tile, 1 = odd
      int cb = (j & 1) * 512 + w * 64;      // wave-uniform chunk base 0..1023
      int c = cb + l;
      int rk = c >> 4, cgk = (c & 15) ^ (rk & 15);
      __builtin_amdgcn_global_load_lds(
          (const GAS void*)(Kh + (sup * 128 + kb * 64 + rk) * EMBED + cgk * 8),
          (LAS void*)(&lKV[buf][kb * 8192 + cb * 8]), 16, 0, 0);
      int rv = c >> 3, cgv = (c & 7) ^ (rv & 7);
      __builtin_amdgcn_global_load_lds(
          (const GAS void*)(Vh + rv * SEQ + sup * 128 + kb * 64 + cgv * 8),
          (LAS void*)(&lKV[buf][16384 + kb * 8192 + cb * 8]), 16, 0, 0);
    }
  };

  // Q fragments in registers (frag layout: m/n=ln, k=quad*8+j); log2e/sqrt(E) folded
  bf16x8 qf[2][4];
#pragma unroll
  for (int rs = 0; rs < 2; ++rs)
#pragma unroll
    for (int kc = 0; kc < 4; ++kc)
      qf[rs][kc] = *(const bf16x8*)(Qh + (q0 + rs * 16 + ln) * EMBED + kc * 32 + quad * 8);

  f32x4 oacc[2][8] = {};
  float rsum[2] = {0.f, 0.f};

  stage(0, 0);  // prologue: 8 gll in flight

  int cur = 0;
#pragma unroll 1
  for (int sup = 0; sup < SEQ / 128; ++sup) {
    if (sup + 1 < SEQ / 128) {
      stage(cur ^ 1, sup + 1);
      asm volatile("s_waitcnt vmcnt(8)" ::: "memory");  // stage(sup) retired
    } else {
      asm volatile("s_waitcnt vmcnt(0)" ::: "memory");
    }
    __builtin_amdgcn_s_barrier();       // all waves' stage(sup) visible
    __builtin_amdgcn_sched_barrier(0);  // no ds_read hoisted above this point

    const u16* myK = &lKV[cur][wk * 8192];
    const u16* myV = &lKV[cur][16384 + wk * 8192];

    // ---- S^T = K'.Q (swapped): lane holds P[key=ns*16+quad*4+r][q=rs*16+ln] --
    f32x4 sacc[2][4] = {};
#pragma unroll
    for (int kc = 0; kc < 4; ++kc) {
      bf16x8 kf[4];
#pragma unroll
      for (int ns = 0; ns < 4; ++ns) {
        int kr = ns * 16 + ln;
        kf[ns] = *(const bf16x8*)(myK + kr * 128 + (((kc * 4 + quad) ^ (kr & 15)) * 8));
      }
      __builtin_amdgcn_s_setprio(1);
#pragma unroll
      for (int ns = 0; ns < 4; ++ns)
#pragma unroll
        for (int rs = 0; rs < 2; ++rs)
          sacc[rs][ns] = __builtin_amdgcn_mfma_f32_16x16x32_bf16(kf[ns], qf[rs][kc],
                                                                 sacc[rs][ns], 0, 0, 0);
      __builtin_amdgcn_s_setprio(0);
    }
    // ---- preload all V fragments from LDS (B-frag: n=e-row, k=key) ----
    bf16x8 vf[2][8];
#pragma unroll
    for (int kc = 0; kc < 2; ++kc)
#pragma unroll
      for (int es = 0; es < 8; ++es) {
        int er = es * 16 + ln;
        vf[kc][es] = *(const bf16x8*)(myV + er * 64 + (((kc * 4 + quad) ^ (er & 7)) * 8));
      }
    // ---- softmax + PA assembly + PV, fully in-register (validated R4/R5) ----
#pragma unroll
    for (int rs = 0; rs < 2; ++rs) {
      float p[4][4];
#pragma unroll
      for (int ns = 0; ns < 4; ++ns)
#pragma unroll
        for (int r = 0; r < 4; ++r) p[ns][r] = exp2f(sacc[rs][ns][r]);
      float s0 = (p[0][0] + p[0][1]) + (p[0][2] + p[0][3]);
      float s1 = (p[1][0] + p[1][1]) + (p[1][2] + p[1][3]);
      float s2 = (p[2][0] + p[2][1]) + (p[2][2] + p[2][3]);
      float s3 = (p[3][0] + p[3][1]) + (p[3][2] + p[3][3]);
      rsum[rs] += (s0 + s1) + (s2 + s3);
#pragma unroll
      for (int kc = 0; kc < 2; ++kc) {
        // ns0 = kc*2 ("a" = keys [kc*32, kc*32+16)), ns1 = kc*2+1 ("b").
        // t = permlane32_swap(a, b); u = permlane16_swap(t.x, t.y):
        // u.x = [a@q0,a@q2,b@q0,b@q2], u.y = [a@q1,a@q3,b@q1,b@q3].
        int n0 = kc * 2, n1 = kc * 2 + 1;
        unsigned a0 = cvt_pk_bf16(p[n0][0], p[n0][1]);
        unsigned a1 = cvt_pk_bf16(p[n0][2], p[n0][3]);
        unsigned b0 = cvt_pk_bf16(p[n1][0], p[n1][1]);
        unsigned b1 = cvt_pk_bf16(p[n1][2], p[n1][3]);
        u32x2 t0 = __builtin_amdgcn_permlane32_swap(a0, b0, false, false);
        u32x2 u0 = __builtin_amdgcn_permlane16_swap(t0.x, t0.y, false, false);
        u32x2 t1 = __builtin_amdgcn_permlane32_swap(a1, b1, false, false);
        u32x2 u1 = __builtin_amdgcn_permlane16_swap(t1.x, t1.y, false, false);
        u32x4 paw = {u0.x, u1.x, u0.y, u1.y};
        bf16x8 pa = __builtin_bit_cast(bf16x8, paw);
        __builtin_amdgcn_s_setprio(1);
#pragma unroll
        for (int es = 0; es < 8; ++es)
          oacc[rs][es] = __builtin_amdgcn_mfma_f32_16x16x32_bf16(pa, vf[kc][es],
                                                                 oacc[rs][es], 0, 0, 0);
        __builtin_amdgcn_s_setprio(0);
      }
    }
    __builtin_amdgcn_sched_barrier(0);
    __builtin_amdgcn_s_barrier();  // all waves done reading lKV[cur]
    cur ^= 1;
  }

  // ---- rowsum: reduce over quads (q=ln), broadcast to oacc row alignment ----
  float srl[2][4];
#pragma unroll
  for (int rs = 0; rs < 2; ++rs) {
    float t = rsum[rs] + __shfl(rsum[rs], l ^ 16);
    t = t + __shfl(t, l ^ 32);
#pragma unroll
    for (int r = 0; r < 4; ++r) srl[rs][r] = __shfl(t, quad * 4 + r);
  }

  // ---- merge wk=1 into wk=0 via LDS (reuses lKV), divide by l, store ----
  __syncthreads();
  float* lO = (float*)lKV;  // [wr][32][132] fp32, wr 0..3 -> 67.6 KB
  if (wk == 1) {
#pragma unroll
    for (int rs = 0; rs < 2; ++rs) {
#pragma unroll
      for (int es = 0; es < 8; ++es)
#pragma unroll
        for (int r = 0; r < 4; ++r)
          lO[wr * 4224 + (rs * 16 + quad * 4 + r) * 132 + es * 16 + ln] = oacc[rs][es][r];
      if (ln == 0)
#pragma unroll
        for (int r = 0; r < 4; ++r)
          lO[wr * 4224 + (rs * 16 + quad * 4 + r) * 132 + 128] = srl[rs][r];
    }
  }
  __syncthreads();
  if (wk == 0) {
#pragma unroll
    for (int rs = 0; rs < 2; ++rs)
#pragma unroll
      for (int r = 0; r < 4; ++r) {
        int lrow = rs * 16 + quad * 4 + r;
        float lsum = srl[rs][r] + lO[wr * 4224 + lrow * 132 + 128];
        float rl = 1.f / lsum;
        int srow = q0 + lrow;
#pragma unroll
        for (int es = 0; es < 8; ++es) {
          float o = oacc[rs][es][r] + lO[wr * 4224 + lrow * 132 + es * 16 + ln];
          Zs[(long)srow * (NHEAD * EMBED) + h * EMBED + es * 16 + ln] = f2b(o * rl);
        }
      }
  }
}

// ---------------- out = Zs · proj, split-K=8 into partials ----------------
__global__ __launch_bounds__(256, 2) void final_gemm_kernel(const u16* __restrict__ Zs,
                                                            const u16* __restrict__ projT,
                                                            float* __restrict__ pbuf) {
  const int t = blockIdx.x;   // m-tile 0..15
  const int kc = blockIdx.y;  // k-chunk 0..7 (256 wide)
  gemm128<float>(Zs + (long)t * 128 * (NHEAD * EMBED) + kc * 256, projT + kc * 256,
                 pbuf + (long)kc * SEQ * EMBED + t * 128 * EMBED,
                 NHEAD * EMBED, NHEAD * EMBED, EMBED, 4, nullptr, nullptr, 1.f);
}

__global__ __launch_bounds__(256) void reduce_kernel(const float* __restrict__ pbuf,
                                                     float* __restrict__ out) {
  int i = (blockIdx.x * 256 + threadIdx.x) * 4;
  float4 s = {0.f, 0.f, 0.f, 0.f};
#pragma unroll
  for (int kc = 0; kc < 8; ++kc) {
    float4 v = *(const float4*)(pbuf + (long)kc * SEQ * EMBED + i);
    s.x += v.x; s.y += v.y; s.z += v.z; s.w += v.w;
  }
  *(float4*)(out + i) = s;
}

extern "C" void kernel_launch(void* const* d_in, const int* in_sizes, int n_in,
                              void* d_out, int out_size, void* d_ws, size_t ws_size,
                              hipStream_t stream) {
  const float* x    = (const float*)d_in[0];
  const float* Wq   = (const float*)d_in[1];
  const float* bq   = (const float*)d_in[2];
  const float* Wk   = (const float*)d_in[3];
  const float* bk   = (const float*)d_in[4];
  const float* Wv   = (const float*)d_in[5];
  const float* bv   = (const float*)d_in[6];
  const float* proj = (const float*)d_in[7];
  float* out = (float*)d_out;

  char* ws = (char*)d_ws;
  // workspace layout (MiB offsets): total 52 MiB.
  // pbuf (8 MiB fp32 partials) aliases xb+Wqt, which are dead after qkv_gemm.
  u16* xb    = (u16*)(ws);                      // 2048x1024 bf16       (4 MiB)
  u16* Wqt   = (u16*)(ws + (4L << 20));         // [16][128][1024]      (4 MiB)
  u16* Wkt   = (u16*)(ws + (8L << 20));         //                      (4 MiB)
  u16* Wvt   = (u16*)(ws + (12L << 20));        //                      (4 MiB)
  u16* projT = (u16*)(ws + (16L << 20));        // [128][2048]          (0.5 MiB)
  u16* Qm    = (u16*)(ws + (17L << 20));        // [16][2048][128]      (8 MiB)
  u16* Km    = (u16*)(ws + (26L << 20));        // [16][2048][128]      (8 MiB)
  u16* Vt    = (u16*)(ws + (35L << 20));        // [16][128][2048]      (8 MiB)
  u16* Zs    = (u16*)(ws + (44L << 20));        // [2048][2048]         (8 MiB)
  float* pbuf = (float*)(ws);                   // [8][2048][128] fp32  (8 MiB, aliased)

  // fused prep: all transposes + x cast in one dispatch
  prep_kernel<<<dim3(6912), dim3(256), 0, stream>>>(x, Wq, Wk, Wv, proj, xb, Wqt,
                                                    Wkt, Wvt, projT);

  qkv_gemm_kernel<<<dim3(16, NHEAD, 3), dim3(256), 0, stream>>>(
      xb, Wqt, Wkt, Wvt, bq, bk, bv, Qm, Km, Vt);

  attn_kernel<<<dim3(256), dim3(512), 0, stream>>>(Qm, Km, Vt, Zs);

  final_gemm_kernel<<<dim3(16, 8), dim3(256), 0, stream>>>(Zs, projT, pbuf);
  reduce_kernel<<<dim3(SEQ * EMBED / 1024), dim3(256), 0, stream>>>(pbuf, out);
}